// Round 6
// baseline (145.296 us; speedup 1.0000x reference)
//
#include <hip/hip_runtime.h>
#include <hip/hip_bf16.h>

#define BN 8
#define NN 2000
#define LL 128
#define EE 2048
#define DIN 258
#define KPAD 264
#define NROWS (BN*NN)
#define PENALTY_V 10.0f
#define NBINS 512
#define CANDCAP 256
#define SPLITK 16
#define ECHUNK (EE/SPLITK)   // 128
#define RPB 4                // rows (waves) per block

// ---------------- Kernel A1: partial Wc = W1@W2 over one K-slice ----------------
__global__ __launch_bounds__(256) void kA1(const float* __restrict__ W1,
                                           const float* __restrict__ b1,
                                           const float* __restrict__ W2,
                                           float* __restrict__ part) {
    __shared__ float As2[8][64];
    const int t = threadIdx.x;
    const int j = t & 127;
    const int half = t >> 7;              // 0 or 1
    const int rg = blockIdx.x >> 4;       // row group 0..32
    const int ks = blockIdx.x & 15;       // K slice 0..15
    const int k0 = rg * 8;
    const int ebase = ks * ECHUNK;
    float acc[4] = {0.f, 0.f, 0.f, 0.f};
    for (int ec = ebase; ec < ebase + ECHUNK; ec += 64) {
        #pragma unroll
        for (int q = 0; q < 2; ++q) {
            int linear = q * 256 + t;
            int r8 = linear >> 6;
            int e  = linear & 63;
            int k  = k0 + r8;
            float v;
            if (k < DIN)       v = W1[k * EE + ec + e];
            else if (k == DIN) v = b1[ec + e];
            else               v = 0.0f;
            As2[r8][e] = v;
        }
        __syncthreads();
        #pragma unroll 8
        for (int e = 0; e < 64; ++e) {
            float w = W2[(ec + e) * LL + j];
            #pragma unroll
            for (int rr = 0; rr < 4; ++rr)
                acc[rr] += As2[half * 4 + rr][e] * w;
        }
        __syncthreads();
    }
    #pragma unroll
    for (int rr = 0; rr < 4; ++rr) {
        int k = k0 + half * 4 + rr;       // < KPAD always (max 263)
        part[(size_t)ks * (KPAD * LL) + k * LL + j] = acc[rr];
    }
}

// ---------------- Kernel A2: reduce partials -> Wc, bc ----------------
__global__ __launch_bounds__(256) void kA2(const float* __restrict__ part,
                                           const float* __restrict__ b2,
                                           float* __restrict__ Wc,
                                           float* __restrict__ bc) {
    const int i = blockIdx.x * 256 + threadIdx.x;   // 0..KPAD*LL-1
    float s = 0.f;
    #pragma unroll
    for (int q = 0; q < SPLITK; ++q) s += part[(size_t)q * (KPAD * LL) + i];
    const int k = i >> 7;
    const int j = i & 127;
    if (k == DIN)      { bc[j] = s + b2[j]; Wc[i] = 0.f; }
    else if (k > DIN)  { Wc[i] = 0.f; }
    else               { Wc[i] = s; }
}

// ---- Kernel B: wave-per-row top-128. No __syncthreads: all phases wave-synchronous. ----
// hist word layout: low16 = exclusive-prefix start (after scan), high16 = placed count.
__global__ __launch_bounds__(256) void kB(const float* __restrict__ dist,
                                          const float* __restrict__ theta,
                                          const float* __restrict__ f0,
                                          const float* __restrict__ f1,
                                          float* __restrict__ xin,
                                          int*   __restrict__ gidx) {
    __shared__ __align__(16) unsigned int hist_all[RPB][NBINS];          // 8 KB
    __shared__ __align__(16) unsigned long long cand_all[RPB][CANDCAP];  // 8 KB
    __shared__ __align__(16) float obuf_all[RPB][2 * LL];                // 4 KB
    __shared__ __align__(16) int   oidx_all[RPB][LL];                    // 2 KB
    __shared__ float sdm[RPB];

    const int t = threadIdx.x;
    const int lane = t & 63;
    const int w = t >> 6;
    const int row = blockIdx.x * RPB + w;

    unsigned int* hist = hist_all[w];
    unsigned long long* cand = cand_all[w];
    float* obuf = obuf_all[w];
    int* oidx = oidx_all[w];

    // init hist + cand (wave-local)
    {
        uint4 z4 = {0u, 0u, 0u, 0u};
        #pragma unroll
        for (int q = 0; q < NBINS / 256; ++q)
            *(uint4*)&hist[(lane + q * 64) * 4] = z4;
        unsigned long long f1v = ~0ULL;
        #pragma unroll
        for (int q = 0; q < CANDCAP / 64; ++q)
            cand[lane + q * 64] = f1v;
    }

    // load row into registers: lane gets uint4 q*64+lane (q=0..7), elements (q*64+lane)*4+c
    unsigned int v[32];
    const int nv = (lane < 52) ? 32 : 28;    // 500 uint4 = 7*64 + 52
    {
        const uint4* drow4 = (const uint4*)(dist + (size_t)row * NN);
        #pragma unroll
        for (int q = 0; q < 8; ++q) {
            int qi = q * 64 + lane;
            if (qi < NN / 4) {
                uint4 a = drow4[qi];
                v[4 * q]     = a.x;
                v[4 * q + 1] = a.y;
                v[4 * q + 2] = a.z;
                v[4 * q + 3] = a.w;
            }
        }
    }

    // wave max (uint-bit max == float max for positive floats)
    unsigned int lmax = 0u;
    #pragma unroll
    for (int k = 0; k < 32; ++k) if (k < nv) lmax = max(lmax, v[k]);
    #pragma unroll
    for (int d = 1; d < 64; d <<= 1) lmax = max(lmax, (unsigned int)__shfl_xor((int)lmax, d));
    const float scale = (float)(NBINS - 1) / __uint_as_float(lmax);

    // histogram (counts in low16 region via +1)
    #pragma unroll
    for (int k = 0; k < 32; ++k) {
        if (k < nv) {
            float f = __uint_as_float(v[k]);
            int b = (int)(f * scale);
            b = b > NBINS - 1 ? NBINS - 1 : b;
            atomicAdd(&hist[b], 1u);
        }
    }

    // wave-synchronous exclusive scan: 8 consecutive bins per lane
    {
        uint4* h4 = (uint4*)&hist[lane * 8];
        uint4 a0 = h4[0], a1 = h4[1];
        unsigned int c[8] = {a0.x, a0.y, a0.z, a0.w, a1.x, a1.y, a1.z, a1.w};
        unsigned int loc[8], run = 0;
        #pragma unroll
        for (int k = 0; k < 8; ++k) { loc[k] = run; run += c[k]; }
        unsigned int inc = run;
        #pragma unroll
        for (int d = 1; d < 64; d <<= 1) {
            unsigned int o = (unsigned int)__shfl_up((int)inc, d);
            if (lane >= d) inc += o;
        }
        const unsigned int excl = inc - run;
        uint4 s0 = {excl + loc[0], excl + loc[1], excl + loc[2], excl + loc[3]};
        uint4 s1 = {excl + loc[4], excl + loc[5], excl + loc[6], excl + loc[7]};
        h4[0] = s0; h4[1] = s1;
    }

    // placement: one atomic gives start test + slot; only buckets with start<128 matter
    #pragma unroll
    for (int k = 0; k < 32; ++k) {
        if (k < nv) {
            unsigned int bits = v[k];
            float f = __uint_as_float(bits);
            int b = (int)(f * scale);
            b = b > NBINS - 1 ? NBINS - 1 : b;
            unsigned int old = atomicAdd(&hist[b], 0x10000u);
            unsigned int start = old & 0xFFFFu;
            if (start < (unsigned int)LL) {
                unsigned int slot = start + (old >> 16);
                unsigned int idx = (unsigned int)((k >> 2) * 256 + lane * 4 + (k & 3));
                if (slot < (unsigned int)CANDCAP)
                    cand[slot] = ((unsigned long long)bits << 32) | idx;
            }
        }
    }

    // rank-within-bucket; theta gather issued before rank loop to hide latency
    #pragma unroll
    for (int s = 0; s < CANDCAP / 64; ++s) {
        unsigned long long key = cand[lane + s * 64];
        if (key != ~0ULL) {
            unsigned int bits = (unsigned int)(key >> 32);
            unsigned int idx  = (unsigned int)key;
            float th = theta[(size_t)row * NN + idx];     // early issue
            float f = __uint_as_float(bits);
            int b = (int)(f * scale);
            b = b > NBINS - 1 ? NBINS - 1 : b;
            unsigned int word = hist[b];
            unsigned int start = word & 0xFFFFu;
            unsigned int end = start + (word >> 16);
            if (end > (unsigned int)CANDCAP) end = (unsigned int)CANDCAP;
            unsigned int r = start;
            for (unsigned int j = start; j < end; ++j) r += (cand[j] < key);
            if (r < (unsigned int)LL) {
                obuf[r] = f;
                obuf[LL + r] = th;
                oidx[r] = (int)idx;
                if (r == LL - 1) sdm[w] = f;
            }
        }
    }

    // emit (coalesced): xrow[0..127]=dist/dmax, [128..255]=theta, [256..263]=features+pad
    {
        const float rdm = 1.0f / sdm[w];
        float* xrow = xin + (size_t)row * KPAD;
        float4 o = *(float4*)&obuf[lane * 4];
        if (lane < 32) { o.x *= rdm; o.y *= rdm; o.z *= rdm; o.w *= rdm; }
        *(float4*)&xrow[lane * 4] = o;
        if (lane == 0) {
            xrow[256] = f0[row];
            xrow[257] = f1[row];
            #pragma unroll
            for (int z = DIN; z < KPAD; ++z) xrow[z] = 0.0f;
        }
        int2 g = *(int2*)&oidx[lane * 2];
        *(int2*)&gidx[(size_t)row * LL + lane * 2] = g;
    }
}

// ---------------- Kernel C: val = xin @ Wc + bc - dn  (fp32 SGEMM, 128x128 tiles) ----------------
__global__ __launch_bounds__(256) void kC(const float* __restrict__ xin,
                                          const float* __restrict__ Wc,
                                          const float* __restrict__ bc,
                                          float* __restrict__ val) {
    __shared__ __align__(16) float As[8][132];
    __shared__ __align__(16) float Bs[8][128];
    const int t = threadIdx.x;
    const int tr = t >> 4, tc = t & 15;
    const int row0 = blockIdx.x * 128;
    float acc[8][8];
    #pragma unroll
    for (int i = 0; i < 8; ++i)
        #pragma unroll
        for (int j = 0; j < 8; ++j) acc[i][j] = 0.f;

    for (int kc = 0; kc < KPAD; kc += 8) {
        #pragma unroll
        for (int q = 0; q < 4; ++q) {
            int linear = q * 256 + t;
            int m = linear >> 3, k = linear & 7;
            As[k][m] = xin[(size_t)(row0 + m) * KPAD + kc + k];
        }
        #pragma unroll
        for (int q = 0; q < 4; ++q) {
            int linear = q * 256 + t;
            int k = linear >> 7, c = linear & 127;
            Bs[k][c] = Wc[(kc + k) * LL + c];
        }
        __syncthreads();
        #pragma unroll
        for (int k = 0; k < 8; ++k) {
            float a[8], b[8];
            *(float4*)&a[0] = *(const float4*)&As[k][tr * 8];
            *(float4*)&a[4] = *(const float4*)&As[k][tr * 8 + 4];
            *(float4*)&b[0] = *(const float4*)&Bs[k][tc * 8];
            *(float4*)&b[4] = *(const float4*)&Bs[k][tc * 8 + 4];
            #pragma unroll
            for (int i = 0; i < 8; ++i)
                #pragma unroll
                for (int j = 0; j < 8; ++j)
                    acc[i][j] += a[i] * b[j];
        }
        __syncthreads();
    }
    #pragma unroll
    for (int i = 0; i < 8; ++i) {
        int r = row0 + tr * 8 + i;
        #pragma unroll
        for (int j = 0; j < 8; ++j) {
            int c = tc * 8 + j;
            val[(size_t)r * LL + c] = acc[i][j] + bc[c] - xin[(size_t)r * KPAD + c];
        }
    }
}

// ---------------- Kernel D: fill PENALTY row + scatter, stream out ----------------
__global__ __launch_bounds__(256) void kD(const int* __restrict__ gidx,
                                          const float* __restrict__ val,
                                          float* __restrict__ out) {
    __shared__ __align__(16) float rowbuf[NN];
    const int t = threadIdx.x;
    const int row = blockIdx.x;
    for (int i = t; i < NN; i += 256) rowbuf[i] = PENALTY_V;
    __syncthreads();
    if (t < 128) rowbuf[gidx[(size_t)row * LL + t]] = val[(size_t)row * LL + t];
    __syncthreads();
    float4* out4 = (float4*)(out + (size_t)row * NN);
    const float4* rb4 = (const float4*)rowbuf;
    for (int q = t; q < NN / 4; q += 256) out4[q] = rb4[q];
}

extern "C" void kernel_launch(void* const* d_in, const int* in_sizes, int n_in,
                              void* d_out, int out_size, void* d_ws, size_t ws_size,
                              hipStream_t stream) {
    const float* theta = (const float*)d_in[0];
    const float* dist  = (const float*)d_in[1];
    const float* f0    = (const float*)d_in[2];
    const float* f1    = (const float*)d_in[3];
    const float* W1    = (const float*)d_in[4];
    const float* b1    = (const float*)d_in[5];
    const float* W2    = (const float*)d_in[6];
    const float* b2    = (const float*)d_in[7];
    float* out = (float*)d_out;

    char* ws = (char*)d_ws;
    float* Wc   = (float*)ws;                                   // KPAD*128*4 = 135168
    float* bc   = (float*)(ws + 135168);                        // 512
    float* xin  = (float*)(ws + 135680);                        // NROWS*KPAD*4 = 16896000
    int*   gidx = (int*)  (ws + 135680 + 16896000);             // NROWS*128*4 = 8192000
    float* val  = (float*)(ws + 135680 + 16896000 + 8192000);   // NROWS*128*4 = 8192000
    // part aliases val: kA1 writes it, kA2 consumes it, kC later overwrites val.
    float* part = val;                                          // SPLITK*KPAD*128*4 = 2162688 <= 8192000

    kA1<<<33 * SPLITK, 256, 0, stream>>>(W1, b1, W2, part);
    kA2<<<(KPAD * LL) / 256, 256, 0, stream>>>(part, b2, Wc, bc);
    kB<<<NROWS / RPB, 256, 0, stream>>>(dist, theta, f0, f1, xin, gidx);
    kC<<<NROWS / 128, 256, 0, stream>>>(xin, Wc, bc, val);
    kD<<<NROWS, 256, 0, stream>>>(gidx, val, out);
}